// Round 11
// baseline (916.783 us; speedup 1.0000x reference)
//
#include <hip/hip_runtime.h>
#include <math.h>

// ---------------- problem constants ----------------
#define B_  64
#define S_  128
#define H_  128
#define D_  300
#define L_  20
#define G4  512                 // 4*H
#define SH  (S_*H_)             // 16384
#define BSH ((size_t)B_*SH)     // 1048576
#define EPSV 1e-8f

typedef __attribute__((ext_vector_type(8))) short bshort8;   // 8 bf16 (4 VGPR)
typedef __attribute__((ext_vector_type(4))) float f32x4;     // MFMA C/D

// monotonic float<->uint mapping for atomicMax on floats (handles negatives)
__device__ __forceinline__ unsigned fmap(float f){
  unsigned u = __float_as_uint(f);
  return (u & 0x80000000u) ? ~u : (u | 0x80000000u);
}
__device__ __forceinline__ float funmap(unsigned u){
  return __uint_as_float((u & 0x80000000u) ? (u & 0x7fffffffu) : ~u);
}
__device__ __forceinline__ float sigmf(float x){ return 1.f/(1.f+expf(-x)); }
// NaN-safe fast activations (__expf; gates here are O(1), err ~1e-6)
__device__ __forceinline__ float fsigm(float x){ return 1.f/(1.f+__expf(-x)); }
__device__ __forceinline__ float ftanh(float x){ return 1.f - 2.f/(__expf(2.f*x)+1.f); }
__device__ __forceinline__ float dot4(float4 a, float4 b){
  return a.x*b.x + a.y*b.y + a.z*b.z + a.w*b.w;
}
// fp32 -> bf16 round-to-nearest-even
__device__ __forceinline__ unsigned short f2bf(float f){
  unsigned u = __float_as_uint(f);
  unsigned r = u + 0x7fffu + ((u >> 16) & 1u);
  return (unsigned short)(r >> 16);
}
__device__ __forceinline__ float bf2f(unsigned short us){
  return __uint_as_float(((unsigned)us) << 16);
}
// XOR swizzles: row-major [row][cols], float4-index XOR'd with (row>>3)
__device__ __forceinline__ int swz64(int row, int h){   // 64 cols
  return (row << 6) + ((((h >> 2) ^ ((row >> 3) & 15)) << 2) | (h & 3));
}
__device__ __forceinline__ int swz128(int row, int h){  // 128 cols
  return (row << 7) + ((((h >> 2) ^ ((row >> 3) & 15)) << 2) | (h & 3));
}
// bf16 LDS swizzle: row-major [128 rows][128 h] halfwords; 16B slot XOR row&15
__device__ __forceinline__ int bswz(int row, int slot){  // slot = h>>3
  return (row << 7) + (((slot ^ (row & 15)) << 3));
}
// split fp32 -> (hi,lo) bf16 packs: 8 floats -> 2x int4 (8 bf16 each)
__device__ __forceinline__ void cvt8(float4 a0, float4 a1, int4& hi, int4& lo){
  float v[8] = {a0.x, a0.y, a0.z, a0.w, a1.x, a1.y, a1.z, a1.w};
  unsigned short h[8], l[8];
  #pragma unroll
  for (int i = 0; i < 8; i++) {
    h[i] = f2bf(v[i]);
    float d = v[i] - bf2f(h[i]);
    l[i] = f2bf(d);
  }
  hi = make_int4((unsigned)h[0] | ((unsigned)h[1] << 16), (unsigned)h[2] | ((unsigned)h[3] << 16),
                 (unsigned)h[4] | ((unsigned)h[5] << 16), (unsigned)h[6] | ((unsigned)h[7] << 16));
  lo = make_int4((unsigned)l[0] | ((unsigned)l[1] << 16), (unsigned)l[2] | ((unsigned)l[3] << 16),
                 (unsigned)l[4] | ((unsigned)l[5] << 16), (unsigned)l[6] | ((unsigned)l[7] << 16));
}

// ---------------- embedding gather ----------------
__global__ void k_embed(const float* __restrict__ emb, const int* __restrict__ p,
                        const int* __restrict__ h, float* __restrict__ x1,
                        float* __restrict__ x2)
{
  int row = blockIdx.x;
  const int* idx = blockIdx.y ? h : p;
  float* x = blockIdx.y ? x2 : x1;
  int tok = idx[row];
  const float* src = emb + (size_t)tok * D_;
  float* dst = x + (size_t)row * D_;
  for (int d = threadIdx.x; d < D_; d += blockDim.x) dst[d] = src[d];
}

// ---------------- GEMM (split-bf16 MFMA): C = A(M,K) * W(N,K)^T + bias ----
// PERM=true: output column n holds gate row p(n)=(n&3)*128+(n>>2) -- i.e.
// xg is produced in ri = 4*hidx+gt order so k_lstm's MFMA accumulator lanes
// get all 4 gates of one h-index contiguously. Pure W-row/bias permutation.
template<int K, bool PERM>
__global__ __launch_bounds__(512, 1) void gemm_abt(
    const float* __restrict__ A0, const float* __restrict__ A1,
    const float* __restrict__ W0, const float* __restrict__ W1,
    const float* __restrict__ b0, const float* __restrict__ b1,
    float* __restrict__ Cbase, int M, int N)
{
  int q = blockIdx.z;
  const float* A = (q >> 1) ? A1 : A0;
  const float* W = (q & 1) ? W1 : W0;
  const float* bias = (q & 1) ? b1 : b0;
  float* Cm = Cbase + (size_t)q * M * N;

  __shared__ __align__(16) short AsH[128 * 32];
  __shared__ __align__(16) short AsL[128 * 32];
  __shared__ __align__(16) short WsH[128 * 32];
  __shared__ __align__(16) short WsL[128 * 32];

  int t = threadIdx.x;
  int w = t >> 6, lane = t & 63;
  int r = lane & 15, g = lane >> 4;
  int m0 = blockIdx.x * 128, n0 = blockIdx.y * 128;
  int mbase = (w & 1) * 64;        // 4 m-tiles of 16
  int nbase = (w >> 1) * 32;       // 2 n-tiles of 16

  f32x4 acc[4][2];
  #pragma unroll
  for (int i = 0; i < 4; i++)
    #pragma unroll
    for (int j = 0; j < 2; j++) acc[i][j] = (f32x4){0.f, 0.f, 0.f, 0.f};

  int srow = t >> 2, skc = t & 3;                     // staging: row, k-chunk
  int soff = srow * 32 + ((skc ^ ((srow >> 1) & 3)) << 3);
  int nrow = n0 + srow;
  int wrow = PERM ? ((nrow & 3) * 128 + (nrow >> 2)) : nrow;

  #pragma unroll 1
  for (int k0 = 0; k0 < K; k0 += 32) {
    {
      int gk = k0 + (skc << 3);
      float4 z = make_float4(0.f, 0.f, 0.f, 0.f);
      float4 a0v = z, a1v = z, w0v = z, w1v = z;
      if (gk < K) {
        a0v = *(const float4*)&A[(size_t)(m0 + srow) * K + gk];
        w0v = *(const float4*)&W[(size_t)wrow * K + gk];
      }
      if (gk + 4 < K) {
        a1v = *(const float4*)&A[(size_t)(m0 + srow) * K + gk + 4];
        w1v = *(const float4*)&W[(size_t)wrow * K + gk + 4];
      }
      int4 hi, lo;
      cvt8(a0v, a1v, hi, lo);
      *(int4*)&AsH[soff] = hi; *(int4*)&AsL[soff] = lo;
      cvt8(w0v, w1v, hi, lo);
      *(int4*)&WsH[soff] = hi; *(int4*)&WsL[soff] = lo;
    }
    __syncthreads();
    bshort8 ah[4], al[4], bh[2], bl[2];
    #pragma unroll
    for (int i = 0; i < 4; i++) {
      int R = mbase + i * 16 + r;
      int off = R * 32 + ((g ^ ((R >> 1) & 3)) << 3);
      ah[i] = *(const bshort8*)&AsH[off];
      al[i] = *(const bshort8*)&AsL[off];
    }
    #pragma unroll
    for (int j = 0; j < 2; j++) {
      int R = nbase + j * 16 + r;
      int off = R * 32 + ((g ^ ((R >> 1) & 3)) << 3);
      bh[j] = *(const bshort8*)&WsH[off];
      bl[j] = *(const bshort8*)&WsL[off];
    }
    #pragma unroll
    for (int i = 0; i < 4; i++)
      #pragma unroll
      for (int j = 0; j < 2; j++) {
        acc[i][j] = __builtin_amdgcn_mfma_f32_16x16x32_bf16(ah[i], bh[j], acc[i][j], 0, 0, 0);
        acc[i][j] = __builtin_amdgcn_mfma_f32_16x16x32_bf16(ah[i], bl[j], acc[i][j], 0, 0, 0);
        acc[i][j] = __builtin_amdgcn_mfma_f32_16x16x32_bf16(al[i], bh[j], acc[i][j], 0, 0, 0);
      }
    __syncthreads();
  }
  // epilogue: C/D layout col=lane&15, row=(lane>>4)*4+reg (HW-verified)
  #pragma unroll
  for (int j = 0; j < 2; j++) {
    int gcol = n0 + nbase + j * 16 + r;
    float bv = bias[PERM ? ((gcol & 3) * 128 + (gcol >> 2)) : gcol];
    #pragma unroll
    for (int i = 0; i < 4; i++) {
      #pragma unroll
      for (int rg = 0; rg < 4; rg++) {
        int grow = m0 + mbase + i * 16 + g * 4 + rg;
        Cm[(size_t)grow * N + gcol] = acc[i][j][rg] + bv;
      }
    }
  }
}

// ---------------- LSTM scan (batched MFMA) ----------------
// R10 post-mortem: 1-batch-per-block is VALU-issue-bound (~3560 cyc/step),
// invariant under TLP/ILP slicing. R11: 16 batches per block (grid (4,4) =
// 16 blocks), G(512x16) = W @ H via 16x16x32 bf16 MFMA, hi/lo split x3 terms
// (= gemm_abt numerics). W rows permuted to ri=4*hidx+gt (xg pre-permuted by
// gemm PERM) so each lane's accumulator holds all 4 gates of one h-index for
// one batch -> activation fully in-register; c never leaves the lane. H goes
// to next step via packed (hi|lo<<16) u32 LDS buffer, double-buffered, one
// barrier/step. Stride 140 pad -> <=2-way bank conflicts.
__global__ __launch_bounds__(512, 1) void k_lstm(const float* __restrict__ xg,
    const float* __restrict__ whhF, const float* __restrict__ whhB,
    float* __restrict__ hs)
{
  int bt = blockIdx.x, q = blockIdx.y, dir = q & 1;
  const float* whh = dir ? whhB : whhF;
  int t = threadIdx.x;
  int w = t >> 6, lane = t & 63;
  int r15 = lane & 15, g4 = lane >> 4;
  int bcol = r15;                               // batch within tile
  int bglob = bt * 16 + bcol;
  const float* xgq = xg + ((size_t)(q * B_ + bglob)) * (S_ * G4);
  float* outb = hs + ((size_t)(q * B_ + bglob)) * SH;

  // W fragments: wave w owns m-tiles 4w..4w+3 (reordered rows, hi/lo split).
  // A-frag (mt,ks): lane holds W_r[16mt + r15][ks*32 + g4*8 + 0..7].
  bshort8 ahi[4][4], alo[4][4];
  #pragma unroll
  for (int i = 0; i < 4; i++) {
    int mt = w * 4 + i;
    int grow = (r15 & 3) * 128 + mt * 4 + (r15 >> 2);   // p(16mt + r15)
    #pragma unroll
    for (int ks = 0; ks < 4; ks++) {
      int k0 = ks * 32 + g4 * 8;
      float4 v0 = *(const float4*)&whh[(size_t)grow * 128 + k0];
      float4 v1 = *(const float4*)&whh[(size_t)grow * 128 + k0 + 4];
      int4 hi, lo;
      cvt8(v0, v1, hi, lo);
      ahi[i][ks] = *(bshort8*)&hi;
      alo[i][ks] = *(bshort8*)&lo;
    }
  }

  __shared__ unsigned Hu[2 * 16 * 140];   // [buf][batch][k] = hi | lo<<16
  for (int i = t; i < 2 * 16 * 140; i += 512) Hu[i] = 0u;
  float creg[4] = {0.f, 0.f, 0.f, 0.f};
  __syncthreads();

  float4 xcur[4], xnxt[4];
  {
    int tt0 = dir ? (S_ - 1) : 0;
    #pragma unroll
    for (int i = 0; i < 4; i++)
      xnxt[i] = *(const float4*)&xgq[(size_t)tt0 * G4 + 16 * (w * 4 + i) + 4 * g4];
  }

  #pragma unroll 1
  for (int st = 0; st < S_; st++) {
    int tt = dir ? (S_ - 1 - st) : st;
    int cur = st & 1, nxt = cur ^ 1;
    #pragma unroll
    for (int i = 0; i < 4; i++) xcur[i] = xnxt[i];
    {
      int stn = (st + 1 < S_) ? st + 1 : st;
      int ttn = dir ? (S_ - 1 - stn) : stn;
      #pragma unroll
      for (int i = 0; i < 4; i++)
        xnxt[i] = *(const float4*)&xgq[(size_t)ttn * G4 + 16 * (w * 4 + i) + 4 * g4];
    }
    f32x4 acc[4];
    #pragma unroll
    for (int i = 0; i < 4; i++) acc[i] = (f32x4){0.f, 0.f, 0.f, 0.f};
    #pragma unroll
    for (int ks = 0; ks < 4; ks++) {
      int k0 = ks * 32 + g4 * 8;
      int base = cur * 2240 + bcol * 140 + k0;
      int4 p0 = *(const int4*)&Hu[base];
      int4 p1 = *(const int4*)&Hu[base + 4];
      int4 hi4, lo4;
      hi4.x = (p0.x & 0xffff) | (p0.y << 16);
      hi4.y = (p0.z & 0xffff) | (p0.w << 16);
      hi4.z = (p1.x & 0xffff) | (p1.y << 16);
      hi4.w = (p1.z & 0xffff) | (p1.w << 16);
      lo4.x = (int)(((unsigned)p0.x >> 16) | ((unsigned)p0.y & 0xffff0000u));
      lo4.y = (int)(((unsigned)p0.z >> 16) | ((unsigned)p0.w & 0xffff0000u));
      lo4.z = (int)(((unsigned)p1.x >> 16) | ((unsigned)p1.y & 0xffff0000u));
      lo4.w = (int)(((unsigned)p1.z >> 16) | ((unsigned)p1.w & 0xffff0000u));
      bshort8 bhi = *(bshort8*)&hi4;
      bshort8 blo = *(bshort8*)&lo4;
      #pragma unroll
      for (int i = 0; i < 4; i++) {
        acc[i] = __builtin_amdgcn_mfma_f32_16x16x32_bf16(ahi[i][ks], bhi, acc[i], 0, 0, 0);
        acc[i] = __builtin_amdgcn_mfma_f32_16x16x32_bf16(ahi[i][ks], blo, acc[i], 0, 0, 0);
        acc[i] = __builtin_amdgcn_mfma_f32_16x16x32_bf16(alo[i][ks], bhi, acc[i], 0, 0, 0);
      }
    }
    #pragma unroll
    for (int i = 0; i < 4; i++) {
      int hidx = (w * 4 + i) * 4 + g4;
      float gi = acc[i][0] + xcur[i].x;
      float gf = acc[i][1] + xcur[i].y;
      float gg = acc[i][2] + xcur[i].z;
      float go = acc[i][3] + xcur[i].w;
      float ig = fsigm(gi), fg = fsigm(gf);
      float gv = ftanh(gg), og = fsigm(go);
      creg[i] = fg * creg[i] + ig * gv;
      float hn = og * ftanh(creg[i]);
      outb[(size_t)tt * H_ + hidx] = hn;
      unsigned short hhi = f2bf(hn);
      unsigned short hlo = f2bf(hn - bf2f(hhi));
      Hu[nxt * 2240 + bcol * 140 + hidx] = (unsigned)hhi | ((unsigned)hlo << 16);
    }
    __syncthreads();
  }
}

// ---------------- full matching ----------------
__global__ __launch_bounds__(256) void k_full(const float* __restrict__ C,
    const float* __restrict__ w1, const float* __restrict__ w2,
    float* __restrict__ ag1, float* __restrict__ ag2)
{
  int b = blockIdx.x, q = blockIdx.y, dir = q & 1;
  const float* p1  = C + (size_t)q * BSH + (size_t)b * SH;
  const float* p2l = C + (size_t)((q + 2) & 3) * BSH + (size_t)b * SH + (size_t)(S_ - 1) * H_;
  const float* w = dir ? w2 : w1;
  float* out = (q < 2 ? ag1 : ag2) + (size_t)b * S_ * 160;

  __shared__ float p1s[SH];
  __shared__ float ws2[H_][L_];
  __shared__ float p2s[H_];
  __shared__ float n2s[L_];
  int t = threadIdx.x;
  for (int i = t; i < SH; i += 256) p1s[i] = p1[i];
  for (int i = t; i < H_ * L_; i += 256) { float v = w[i]; ws2[i / L_][i % L_] = v * v; }
  if (t < H_) p2s[t] = p2l[t];
  __syncthreads();
  if (t < L_) {
    float s = 0.f;
    for (int hh = 0; hh < H_; hh++) { float v = p2s[hh]; s += v * v * ws2[hh][t]; }
    n2s[t] = sqrtf(s);
  }
  __syncthreads();
  for (int i = t; i < S_ * L_; i += 256) {
    int s = i / L_, l = i % L_;
    const float* pr = p1s + s * H_;
    float dot = 0.f, n1 = 0.f;
    for (int hh = 0; hh < H_; hh++) {
      float a = pr[hh], ww = ws2[hh][l];
      dot += a * p2s[hh] * ww;
      n1 += a * a * ww;
    }
    n1 = sqrtf(n1);
    out[(size_t)s * 160 + dir * L_ + l] = dot / (fmaxf(n1, EPSV) * fmaxf(n2s[l], EPSV));
  }
}

// ---------------- maxpool matching (bf16 MFMA) ----------------
__global__ __launch_bounds__(512, 1) void k_maxpool(const float* __restrict__ C,
    const float* __restrict__ w3, const float* __restrict__ w4,
    float* __restrict__ ag1, float* __restrict__ ag2)
{
  int b = blockIdx.x, dir = blockIdx.y, lh = blockIdx.z;
  const float* p1 = C + (size_t)(0 + dir) * BSH + (size_t)b * SH;
  const float* p2 = C + (size_t)(2 + dir) * BSH + (size_t)b * SH;
  const float* w = dir ? w4 : w3;

  __shared__ __align__(16) short P1b[128 * 128];
  __shared__ __align__(16) short P2b[128 * 128];
  __shared__ __align__(16) short Ab[128 * 128];
  __shared__ float w2s[128 * 10];
  __shared__ float n1s[128], n2s[128];
  __shared__ unsigned mx2u[128];

  int t = threadIdx.x;
  int wv = t >> 6, lane = t & 63;
  int g = lane >> 4, col = lane & 15;

  for (int i = t; i < 8192; i += 512) {
    int row = i >> 6, hp = i & 63;
    int phys = bswz(row, hp >> 2) + ((hp & 3) << 1);
    float2 v1 = *(const float2*)&p1[(row << 7) + (hp << 1)];
    float2 v2 = *(const float2*)&p2[(row << 7) + (hp << 1)];
    *(unsigned*)&P1b[phys] = (unsigned)f2bf(v1.x) | ((unsigned)f2bf(v1.y) << 16);
    *(unsigned*)&P2b[phys] = (unsigned)f2bf(v2.x) | ((unsigned)f2bf(v2.y) << 16);
  }
  for (int i = t; i < 128 * 10; i += 512) {
    int hh = i / 10, lq = i % 10;
    float wv_ = w[hh * L_ + lh * 10 + lq];
    w2s[i] = wv_ * wv_;
  }
  __syncthreads();

  #pragma unroll 1
  for (int lq = 0; lq < 10; lq++) {
    int lout = lh * 10 + lq;
    for (int i = t; i < 8192; i += 512) {
      int row = i >> 6, hp = i & 63;
      int phys = bswz(row, hp >> 2) + ((hp & 3) << 1);
      unsigned u = *(const unsigned*)&P1b[phys];
      float lo = bf2f((unsigned short)(u & 0xffffu)) * w2s[(hp << 1) * 10 + lq];
      float hi = bf2f((unsigned short)(u >> 16))     * w2s[((hp << 1) + 1) * 10 + lq];
      *(unsigned*)&Ab[phys] = (unsigned)f2bf(lo) | ((unsigned)f2bf(hi) << 16);
    }
    {
      int s = t >> 2, part = t & 3;
      float s1 = 0.f, s2 = 0.f;
      #pragma unroll 1
      for (int hp = part * 16; hp < part * 16 + 16; hp++) {
        int phys = bswz(s, hp >> 2) + ((hp & 3) << 1);
        unsigned u1 = *(const unsigned*)&P1b[phys];
        unsigned u2 = *(const unsigned*)&P2b[phys];
        float wlo = w2s[(hp << 1) * 10 + lq];
        float whi = w2s[((hp << 1) + 1) * 10 + lq];
        float a = bf2f((unsigned short)(u1 & 0xffffu)), bb = bf2f((unsigned short)(u1 >> 16));
        float c2 = bf2f((unsigned short)(u2 & 0xffffu)), d2 = bf2f((unsigned short)(u2 >> 16));
        s1 += a * a * wlo + bb * bb * whi;
        s2 += c2 * c2 * wlo + d2 * d2 * whi;
      }
      s1 += __shfl_xor(s1, 1, 64); s1 += __shfl_xor(s1, 2, 64);
      s2 += __shfl_xor(s2, 1, 64); s2 += __shfl_xor(s2, 2, 64);
      if (part == 0) { n1s[s] = sqrtf(s1); n2s[s] = sqrtf(s2); }
    }
    if (t < 128) mx2u[t] = fmap(-3.4e38f);
    __syncthreads();

    {
      int mrow = (wv << 4) + col;
      f32x4 acc0 = {0,0,0,0}, acc1 = {0,0,0,0}, acc2 = {0,0,0,0}, acc3 = {0,0,0,0};
      f32x4 acc4 = {0,0,0,0}, acc5 = {0,0,0,0}, acc6 = {0,0,0,0}, acc7 = {0,0,0,0};
      #pragma unroll 1
      for (int k0 = 0; k0 < 128; k0 += 32) {
        int slot = ((k0 >> 3) + g) ^ col;
        bshort8 av = *(const bshort8*)&Ab[(mrow << 7) + (slot << 3)];
        bshort8 bv0 = *(const bshort8*)&P2b[((0 << 4) + col << 7) + (slot << 3)];
        bshort8 bv1 = *(const bshort8*)&P2b[(((1 << 4) + col) << 7) + (slot << 3)];
        bshort8 bv2 = *(const bshort8*)&P2b[(((2 << 4) + col) << 7) + (slot << 3)];
        bshort8 bv3 = *(const bshort8*)&P2b[(((3 << 4) + col) << 7) + (slot << 3)];
        bshort8 bv4 = *(const bshort8*)&P2b[(((4 << 4) + col) << 7) + (slot << 3)];
        bshort8 bv5 = *(const bshort8*)&P2b[(((5 << 4) + col) << 7) + (slot << 3)];
        bshort8 bv6 = *(const bshort8*)&P2b[(((6 << 4) + col) << 7) + (slot << 3)];
        bshort8 bv7 = *(const bshort8*)&P2b[(((7 << 4) + col) << 7) + (slot << 3)];
        acc0 = __builtin_amdgcn_mfma_f32_16x16x32_bf16(av, bv0, acc0, 0, 0, 0);
        acc1 = __builtin_amdgcn_mfma_f32_16x16x32_bf16(av, bv1, acc1, 0, 0, 0);
        acc2 = __builtin_amdgcn_mfma_f32_16x16x32_bf16(av, bv2, acc2, 0, 0, 0);
        acc3 = __builtin_amdgcn_mfma_f32_16x16x32_bf16(av, bv3, acc3, 0, 0, 0);
        acc4 = __builtin_amdgcn_mfma_f32_16x16x32_bf16(av, bv4, acc4, 0, 0, 0);
        acc5 = __builtin_amdgcn_mfma_f32_16x16x32_bf16(av, bv5, acc5, 0, 0, 0);
        acc6 = __builtin_amdgcn_mfma_f32_16x16x32_bf16(av, bv6, acc6, 0, 0, 0);
        acc7 = __builtin_amdgcn_mfma_f32_16x16x32_bf16(av, bv7, acc7, 0, 0, 0);
      }
      float n1v[4];
      #pragma unroll
      for (int r = 0; r < 4; r++) n1v[r] = n1s[(wv << 4) + (g << 2) + r];
      float rm[4] = {-3.4e38f, -3.4e38f, -3.4e38f, -3.4e38f};
      float cm[8];
      f32x4 accs[8] = {acc0, acc1, acc2, acc3, acc4, acc5, acc6, acc7};
      #pragma unroll
      for (int c = 0; c < 8; c++) {
        float n2v = n2s[(c << 4) + col];
        float cmx = -3.4e38f;
        #pragma unroll
        for (int r = 0; r < 4; r++) {
          float deno = n1v[r] * n2v;
          float cs = accs[c][r] / (deno > EPSV ? deno : EPSV);
          rm[r] = fmaxf(rm[r], cs);
          cmx = fmaxf(cmx, cs);
        }
        cm[c] = cmx;
      }
      #pragma unroll
      for (int m = 1; m < 16; m <<= 1)
        #pragma unroll
        for (int r = 0; r < 4; r++) rm[r] = fmaxf(rm[r], __shfl_xor(rm[r], m, 64));
      if (col == 0) {
        #pragma unroll
        for (int r = 0; r < 4; r++) {
          int srow = (wv << 4) + (g << 2) + r;
          ag1[(size_t)b * S_ * 160 + (size_t)srow * 160 + 40 + dir * L_ + lout] = rm[r];
        }
      }
      #pragma unroll
      for (int c = 0; c < 8; c++) {
        cm[c] = fmaxf(cm[c], __shfl_xor(cm[c], 16, 64));
        cm[c] = fmaxf(cm[c], __shfl_xor(cm[c], 32, 64));
      }
      if (lane < 16) {
        #pragma unroll
        for (int c = 0; c < 8; c++) atomicMax(&mx2u[(c << 4) + lane], fmap(cm[c]));
      }
    }
    __syncthreads();
    if (t < 128)
      ag2[(size_t)b * S_ * 160 + (size_t)t * 160 + 40 + dir * L_ + lout] = funmap(mx2u[t]);
    __syncthreads();
  }
}

// ---------------- alpha (plain cosine matrix) ----------------
__global__ __launch_bounds__(256, 1) void k_alpha(const float* __restrict__ C,
                                                  float* __restrict__ alpha)
{
  int b = blockIdx.x, dir = blockIdx.y;
  const float* p1 = C + (size_t)(0 + dir) * BSH + (size_t)b * SH;
  const float* p2 = C + (size_t)(2 + dir) * BSH + (size_t)b * SH;
  __shared__ __align__(16) float a1[128 * 64];
  __shared__ __align__(16) float a2[128 * 64];
  __shared__ float n1p[128], n2p[128];
  int t = threadIdx.x, tx = t & 15, ty = t >> 4;
  float acc[8][8] = {};

  for (int pass = 0; pass < 2; pass++) {
    int h0 = pass << 6;
    for (int i = t; i < 128 * 64; i += 256) {
      int row = i >> 6, hh = i & 63;
      int off = swz64(row, hh);
      a1[off] = p1[(size_t)row * H_ + h0 + hh];
      a2[off] = p2[(size_t)row * H_ + h0 + hh];
    }
    __syncthreads();
    {
      int r = t & 127;
      const float* a = (t < 128) ? a1 : a2;
      float s = 0.f;
      #pragma unroll 1
      for (int f = 0; f < 16; f++) {
        float4 v = *(const float4*)&a[(r << 6) + ((f ^ ((r >> 3) & 15)) << 2)];
        s += dot4(v, v);
      }
      float* np = (t < 128) ? n1p : n2p;
      if (pass == 0) np[r] = s; else np[r] += s;
    }
    #pragma unroll 1
    for (int f = 0; f < 16; f++) {
      int cx = ((f ^ ty) << 2);
      int cy = ((f ^ tx) << 2);
      float4 x[8], y[8];
      #pragma unroll
      for (int i = 0; i < 8; i++) x[i] = *(const float4*)&a1[((8 * ty + i) << 6) + cx];
      #pragma unroll
      for (int j = 0; j < 8; j++) y[j] = *(const float4*)&a2[((8 * tx + j) << 6) + cy];
      #pragma unroll
      for (int i = 0; i < 8; i++)
        #pragma unroll
        for (int j = 0; j < 8; j++) acc[i][j] += dot4(x[i], y[j]);
    }
    __syncthreads();
  }
  float inv1[8], inv2[8];
  #pragma unroll
  for (int i = 0; i < 8; i++) inv1[i] = 1.f / fmaxf(sqrtf(n1p[8 * ty + i]), EPSV);
  #pragma unroll
  for (int j = 0; j < 8; j++) inv2[j] = 1.f / fmaxf(sqrtf(n2p[8 * tx + j]), EPSV);
  float* outp = alpha + ((size_t)dir * B_ + b) * SH;
  #pragma unroll
  for (int i = 0; i < 8; i++) {
    int ss = 8 * ty + i;
    float s1 = inv1[i];
    float4 o0 = make_float4(acc[i][0] * s1 * inv2[0], acc[i][1] * s1 * inv2[1],
                            acc[i][2] * s1 * inv2[2], acc[i][3] * s1 * inv2[3]);
    float4 o1 = make_float4(acc[i][4] * s1 * inv2[4], acc[i][5] * s1 * inv2[5],
                            acc[i][6] * s1 * inv2[6], acc[i][7] * s1 * inv2[7]);
    *(float4*)&outp[(size_t)ss * S_ + 8 * tx] = o0;
    *(float4*)&outp[(size_t)ss * S_ + 8 * tx + 4] = o1;
  }
}

// ---------------- attentive matching ----------------
__global__ __launch_bounds__(256, 1) void k_att(const float* __restrict__ C,
    const float* __restrict__ alpha,
    const float* __restrict__ w5, const float* __restrict__ w6,
    const float* __restrict__ w7, const float* __restrict__ w8,
    float* __restrict__ ag1, float* __restrict__ ag2)
{
  int b = blockIdx.x, q = blockIdx.y, dir = q & 1;
  const float* p1  = C + (size_t)q * BSH + (size_t)b * SH;
  const float* m2g = C + (size_t)((q + 2) & 3) * BSH + (size_t)b * SH;
  const float* wa = dir ? w6 : w5;
  const float* wm = dir ? w8 : w7;
  const float* ain = alpha + ((size_t)dir * B_ + b) * SH;
  float* out = (q < 2 ? ag1 : ag2) + (size_t)b * S_ * 160;
  bool tr = (q >= 2);

  __shared__ __align__(16) float A[128 * 128];
  __shared__ __align__(16) float M2T[128 * 128];
  __shared__ __align__(16) float waT[20 * 128];
  __shared__ __align__(16) float wmT[20 * 128];
  __shared__ float rowsum[128];
  __shared__ int   midx[128];
  int t = threadIdx.x, tx = t & 15, ty = t >> 4;

  for (int i = t; i < SH; i += 256) {
    int r = i >> 7, c = i & 127;
    float av = ain[i];
    if (tr) A[swz128(c, r)] = av; else A[swz128(r, c)] = av;
    M2T[swz128(c, r)] = m2g[i];
  }
  for (int i = t; i < H_ * L_; i += 256) {
    int hh = i / L_, l = i % L_;
    float v = wa[i]; waT[l * 128 + hh] = v * v;
    float u = wm[i]; wmT[l * 128 + hh] = u * u;
  }
  __syncthreads();

  if (t < 128) {
    float sum = 0.f, best = -3.4e38f; int bi = 0;
    #pragma unroll 1
    for (int f = 0; f < 32; f++) {
      float4 v = *(const float4*)&A[(t << 7) + (((f ^ ((t >> 3) & 15)) & 31) << 2)];
      sum += v.x + v.y + v.z + v.w;
      int k = f << 2;
      if (v.x > best) { best = v.x; bi = k; }
      if (v.y > best) { best = v.y; bi = k + 1; }
      if (v.z > best) { best = v.z; bi = k + 2; }
      if (v.w > best) { best = v.w; bi = k + 3; }
    }
    rowsum[t] = sum; midx[t] = bi;
  }
  __syncthreads();

  float acc[8][8] = {};
  #pragma unroll 1
  for (int f = 0; f < 32; f++) {
    int cx = (((f ^ ty) & 31) << 2);
    int cy = (((f ^ tx) & 31) << 2);
    float4 x[8], y[8];
    #pragma unroll
    for (int i = 0; i < 8; i++) x[i] = *(const float4*)&A[((8 * ty + i) << 7) + cx];
    #pragma unroll
    for (int j = 0; j < 8; j++) y[j] = *(const float4*)&M2T[((8 * tx + j) << 7) + cy];
    #pragma unroll
    for (int i = 0; i < 8; i++)
      #pragma unroll
      for (int j = 0; j < 8; j++) acc[i][j] += dot4(x[i], y[j]);
  }
  __syncthreads();
  {
    float rinv[8];
    #pragma unroll
    for (int i = 0; i < 8; i++) rinv[i] = 1.f / rowsum[8 * ty + i];
    #pragma unroll
    for (int i = 0; i < 8; i++) {
      int row = 8 * ty + i;
      int f0 = (2 * tx) ^ ((row >> 3) & 15);
      int f1 = (2 * tx + 1) ^ ((row >> 3) & 15);
      float4 o0 = make_float4(acc[i][0] * rinv[i], acc[i][1] * rinv[i],
                              acc[i][2] * rinv[i], acc[i][3] * rinv[i]);
      float4 o1 = make_float4(acc[i][4] * rinv[i], acc[i][5] * rinv[i],
                              acc[i][6] * rinv[i], acc[i][7] * rinv[i]);
      *(float4*)&A[(row << 7) + (f0 << 2)] = o0;
      *(float4*)&A[(row << 7) + (f1 << 2)] = o1;
    }
  }
  __syncthreads();

  {
    int s = t >> 1, l0 = (t & 1) * 10;
    int mi = midx[s];
    const float* m2r = m2g + (size_t)mi * H_;
    const float* p1r = p1 + (size_t)s * H_;
    float dA[10] = {}, nA[10] = {}, bA[10] = {};
    float dM[10] = {}, nM[10] = {}, bM[10] = {};
    #pragma unroll 1
    for (int f = 0; f < 32; f++) {
      float4 pv = *(const float4*)&p1r[f << 2];
      float4 mv = *(const float4*)&m2r[f << 2];
      float4 av = *(const float4*)&A[(s << 7) + (((f ^ ((s >> 3) & 15)) & 31) << 2)];
      float4 ap = make_float4(av.x*pv.x, av.y*pv.y, av.z*pv.z, av.w*pv.w);
      float4 a2 = make_float4(av.x*av.x, av.y*av.y, av.z*av.z, av.w*av.w);
      float4 p2 = make_float4(pv.x*pv.x, pv.y*pv.y, pv.z*pv.z, pv.w*pv.w);
      float4 mp = make_float4(mv.x*pv.x, mv.y*pv.y, mv.z*pv.z, mv.w*pv.w);
      float4 m2 = make_float4(mv.x*mv.x, mv.y*mv.y, mv.z*mv.z, mv.w*mv.w);
      #pragma unroll
      for (int l = 0; l < 10; l++) {
        float4 wv = *(const float4*)&waT[(l0 + l) * 128 + (f << 2)];
        dA[l] += dot4(ap, wv); nA[l] += dot4(a2, wv); bA[l] += dot4(p2, wv);
        float4 uv = *(const float4*)&wmT[(l0 + l) * 128 + (f << 2)];
        dM[l] += dot4(mp, uv); nM[l] += dot4(m2, uv); bM[l] += dot4(p2, uv);
      }
    }
    #pragma unroll
    for (int l = 0; l < 10; l++) {
      int ll = l0 + l;
      out[(size_t)s * 160 + 80  + dir * L_ + ll] =
          dA[l] / (fmaxf(sqrtf(nA[l]), EPSV) * fmaxf(sqrtf(bA[l]), EPSV));
      out[(size_t)s * 160 + 120 + dir * L_ + ll] =
          dM[l] / (fmaxf(sqrtf(nM[l]), EPSV) * fmaxf(sqrtf(bM[l]), EPSV));
    }
  }
}

// ---------------- final MLP ----------------
__global__ __launch_bounds__(256) void k_final(const float* __restrict__ Cc,
    const float* __restrict__ pW1, const float* __restrict__ pb1,
    const float* __restrict__ pW2, const float* __restrict__ pb2,
    float* __restrict__ out)
{
  int b = blockIdx.x, t = threadIdx.x;
  __shared__ float cat[512];
  __shared__ float hid[256];
  if (t < 128) {
    cat[t]       = Cc[(size_t)(0 * B_ + b) * SH + (size_t)(S_ - 1) * H_ + t];
    cat[128 + t] = Cc[(size_t)(1 * B_ + b) * SH + (size_t)(S_ - 1) * H_ + t];
    cat[256 + t] = Cc[(size_t)(2 * B_ + b) * SH + (size_t)(S_ - 1) * H_ + t];
    cat[384 + t] = Cc[(size_t)(3 * B_ + b) * SH + (size_t)(S_ - 1) * H_ + t];
  }
  __syncthreads();
  float a = pb1[t];
  for (int k = 0; k < 512; k++) a += cat[k] * pW1[(size_t)t * 512 + k];
  hid[t] = fmaxf(a, 0.f);
  __syncthreads();
  if (t < 3) {
    float o = pb2[t];
    for (int k = 0; k < 256; k++) o += hid[k] * pW2[(size_t)t * 256 + k];
    out[(size_t)b * 3 + t] = o;
  }
}

// ---------------- launch ----------------
extern "C" void kernel_launch(void* const* d_in, const int* in_sizes, int n_in,
                              void* d_out, int out_size, void* d_ws, size_t ws_size,
                              hipStream_t stream)
{
  const float* emb    = (const float*)d_in[0];
  const float* cwih_f = (const float*)d_in[1];
  const float* cwhh_f = (const float*)d_in[2];
  const float* cb_f   = (const float*)d_in[3];
  const float* cwih_b = (const float*)d_in[4];
  const float* cwhh_b = (const float*)d_in[5];
  const float* cb_b   = (const float*)d_in[6];
  const float* awih_f = (const float*)d_in[7];
  const float* awhh_f = (const float*)d_in[8];
  const float* ab_f   = (const float*)d_in[9];
  const float* awih_b = (const float*)d_in[10];
  const float* awhh_b = (const float*)d_in[11];
  const float* ab_b   = (const float*)d_in[12];
  const float* pW1    = (const float*)d_in[13];
  const float* pb1    = (const float*)d_in[14];
  const float* pW2    = (const float*)d_in[15];
  const float* pb2    = (const float*)d_in[16];
  const int*   pidx   = (const int*)d_in[17];
  const int*   hidx   = (const int*)d_in[18];
  const float* w1 = (const float*)d_in[19];
  const float* w2 = (const float*)d_in[20];
  const float* w3 = (const float*)d_in[21];
  const float* w4 = (const float*)d_in[22];
  const float* w5 = (const float*)d_in[23];
  const float* w6 = (const float*)d_in[24];
  const float* w7 = (const float*)d_in[25];
  const float* w8 = (const float*)d_in[26];

  float* ws = (float*)d_ws;
  float* XG   = ws;
  float* X1   = ws + 16777216;
  float* X2   = X1 + 2457600;
  float* ALPH = X1;
  float* AG1  = ws + 16777216 + 2097152;
  float* AG2  = AG1 + (size_t)B_ * S_ * 160;
  float* CC   = ws + 21692416;

  k_embed<<<dim3(B_ * S_, 2), 256, 0, stream>>>(emb, pidx, hidx, X1, X2);
  gemm_abt<D_, true><<<dim3(64, 4, 4), 512, 0, stream>>>(X1, X2, cwih_f, cwih_b, cb_f, cb_b,
                                                         XG, B_ * S_, G4);
  k_lstm<<<dim3(B_ / 16, 4), 512, 0, stream>>>(XG, cwhh_f, cwhh_b, CC);
  k_full<<<dim3(B_, 4), 256, 0, stream>>>(CC, w1, w2, AG1, AG2);
  k_maxpool<<<dim3(B_, 2, 2), 512, 0, stream>>>(CC, w3, w4, AG1, AG2);
  k_alpha<<<dim3(B_, 2), 256, 0, stream>>>(CC, ALPH);
  k_att<<<dim3(B_, 4), 256, 0, stream>>>(CC, ALPH, w5, w6, w7, w8, AG1, AG2);
  gemm_abt<8 * L_, true><<<dim3(64, 4, 4), 512, 0, stream>>>(AG1, AG2, awih_f, awih_b, ab_f, ab_b,
                                                             XG, B_ * S_, G4);
  k_lstm<<<dim3(B_ / 16, 4), 512, 0, stream>>>(XG, awhh_f, awhh_b, CC);
  k_final<<<dim3(B_), 256, 0, stream>>>(CC, pW1, pb1, pW2, pb2, (float*)d_out);
}

// Round 12
// 612.196 us; speedup vs baseline: 1.4975x; 1.4975x over previous
//
#include <hip/hip_runtime.h>
#include <math.h>

// ---------------- problem constants ----------------
#define B_  64
#define S_  128
#define H_  128
#define D_  300
#define L_  20
#define G4  512                 // 4*H
#define SH  (S_*H_)             // 16384
#define BSH ((size_t)B_*SH)     // 1048576
#define EPSV 1e-8f

typedef __attribute__((ext_vector_type(8))) short bshort8;   // 8 bf16 (4 VGPR)
typedef __attribute__((ext_vector_type(4))) float f32x4;     // MFMA C/D

// monotonic float<->uint mapping for atomicMax on floats (handles negatives)
__device__ __forceinline__ unsigned fmap(float f){
  unsigned u = __float_as_uint(f);
  return (u & 0x80000000u) ? ~u : (u | 0x80000000u);
}
__device__ __forceinline__ float funmap(unsigned u){
  return __uint_as_float((u & 0x80000000u) ? (u & 0x7fffffffu) : ~u);
}
__device__ __forceinline__ float sigmf(float x){ return 1.f/(1.f+expf(-x)); }
// NaN-safe fast activations (__expf; gates here are O(1), err ~1e-6).
// Verified numerically safe: R11's k_lstm used these and absmax was unchanged.
__device__ __forceinline__ float fsigm(float x){ return 1.f/(1.f+__expf(-x)); }
__device__ __forceinline__ float ftanh(float x){ return 1.f - 2.f/(__expf(2.f*x)+1.f); }
__device__ __forceinline__ float dot4(float4 a, float4 b){
  return a.x*b.x + a.y*b.y + a.z*b.z + a.w*b.w;
}
// wave-uniform broadcast of lane k's value (SGPR), no LDS pipe
__device__ __forceinline__ float blane(float v, int k){
  return __int_as_float(__builtin_amdgcn_readlane(__float_as_int(v), k));
}
// fp32 -> bf16 round-to-nearest-even
__device__ __forceinline__ unsigned short f2bf(float f){
  unsigned u = __float_as_uint(f);
  unsigned r = u + 0x7fffu + ((u >> 16) & 1u);
  return (unsigned short)(r >> 16);
}
__device__ __forceinline__ float bf2f(unsigned short us){
  return __uint_as_float(((unsigned)us) << 16);
}
// XOR swizzles: row-major [row][cols], float4-index XOR'd with (row>>3)
__device__ __forceinline__ int swz64(int row, int h){   // 64 cols
  return (row << 6) + ((((h >> 2) ^ ((row >> 3) & 15)) << 2) | (h & 3));
}
__device__ __forceinline__ int swz128(int row, int h){  // 128 cols
  return (row << 7) + ((((h >> 2) ^ ((row >> 3) & 15)) << 2) | (h & 3));
}
// bf16 LDS swizzle: row-major [128 rows][128 h] halfwords; 16B slot XOR row&15
__device__ __forceinline__ int bswz(int row, int slot){  // slot = h>>3
  return (row << 7) + (((slot ^ (row & 15)) << 3));
}
// split fp32 -> (hi,lo) bf16 packs: 8 floats -> 2x int4 (8 bf16 each)
__device__ __forceinline__ void cvt8(float4 a0, float4 a1, int4& hi, int4& lo){
  float v[8] = {a0.x, a0.y, a0.z, a0.w, a1.x, a1.y, a1.z, a1.w};
  unsigned short h[8], l[8];
  #pragma unroll
  for (int i = 0; i < 8; i++) {
    h[i] = f2bf(v[i]);
    float d = v[i] - bf2f(h[i]);
    l[i] = f2bf(d);
  }
  hi = make_int4((unsigned)h[0] | ((unsigned)h[1] << 16), (unsigned)h[2] | ((unsigned)h[3] << 16),
                 (unsigned)h[4] | ((unsigned)h[5] << 16), (unsigned)h[6] | ((unsigned)h[7] << 16));
  lo = make_int4((unsigned)l[0] | ((unsigned)l[1] << 16), (unsigned)l[2] | ((unsigned)l[3] << 16),
                 (unsigned)l[4] | ((unsigned)l[5] << 16), (unsigned)l[6] | ((unsigned)l[7] << 16));
}

// ---------------- embedding gather ----------------
__global__ void k_embed(const float* __restrict__ emb, const int* __restrict__ p,
                        const int* __restrict__ h, float* __restrict__ x1,
                        float* __restrict__ x2)
{
  int row = blockIdx.x;
  const int* idx = blockIdx.y ? h : p;
  float* x = blockIdx.y ? x2 : x1;
  int tok = idx[row];
  const float* src = emb + (size_t)tok * D_;
  float* dst = x + (size_t)row * D_;
  for (int d = threadIdx.x; d < D_; d += blockDim.x) dst[d] = src[d];
}

// ---------------- GEMM (split-bf16 MFMA): C = A(M,K) * W(N,K)^T + bias ----
// fp32 emulated as hi+lo bf16; C = Ah*Wh + Ah*Wl + Al*Wh (lo*lo dropped,
// rel err ~2^-17). 128x128 tile, 8 waves as 4(M)x2(N) grid of 16x16 MFMA
// tiles per wave, BK=32.
template<int K>
__global__ __launch_bounds__(512, 1) void gemm_abt(
    const float* __restrict__ A0, const float* __restrict__ A1,
    const float* __restrict__ W0, const float* __restrict__ W1,
    const float* __restrict__ b0, const float* __restrict__ b1,
    float* __restrict__ Cbase, int M, int N)
{
  int q = blockIdx.z;
  const float* A = (q >> 1) ? A1 : A0;
  const float* W = (q & 1) ? W1 : W0;
  const float* bias = (q & 1) ? b1 : b0;
  float* Cm = Cbase + (size_t)q * M * N;

  __shared__ __align__(16) short AsH[128 * 32];
  __shared__ __align__(16) short AsL[128 * 32];
  __shared__ __align__(16) short WsH[128 * 32];
  __shared__ __align__(16) short WsL[128 * 32];

  int t = threadIdx.x;
  int w = t >> 6, lane = t & 63;
  int r = lane & 15, g = lane >> 4;
  int m0 = blockIdx.x * 128, n0 = blockIdx.y * 128;
  int mbase = (w & 1) * 64;        // 4 m-tiles of 16
  int nbase = (w >> 1) * 32;       // 2 n-tiles of 16

  f32x4 acc[4][2];
  #pragma unroll
  for (int i = 0; i < 4; i++)
    #pragma unroll
    for (int j = 0; j < 2; j++) acc[i][j] = (f32x4){0.f, 0.f, 0.f, 0.f};

  int srow = t >> 2, skc = t & 3;                     // staging: row, k-chunk
  int soff = srow * 32 + ((skc ^ ((srow >> 1) & 3)) << 3);

  #pragma unroll 1
  for (int k0 = 0; k0 < K; k0 += 32) {
    {
      int gk = k0 + (skc << 3);
      float4 z = make_float4(0.f, 0.f, 0.f, 0.f);
      float4 a0v = z, a1v = z, w0v = z, w1v = z;
      if (gk < K) {
        a0v = *(const float4*)&A[(size_t)(m0 + srow) * K + gk];
        w0v = *(const float4*)&W[(size_t)(n0 + srow) * K + gk];
      }
      if (gk + 4 < K) {
        a1v = *(const float4*)&A[(size_t)(m0 + srow) * K + gk + 4];
        w1v = *(const float4*)&W[(size_t)(n0 + srow) * K + gk + 4];
      }
      int4 hi, lo;
      cvt8(a0v, a1v, hi, lo);
      *(int4*)&AsH[soff] = hi; *(int4*)&AsL[soff] = lo;
      cvt8(w0v, w1v, hi, lo);
      *(int4*)&WsH[soff] = hi; *(int4*)&WsL[soff] = lo;
    }
    __syncthreads();
    bshort8 ah[4], al[4], bh[2], bl[2];
    #pragma unroll
    for (int i = 0; i < 4; i++) {
      int R = mbase + i * 16 + r;
      int off = R * 32 + ((g ^ ((R >> 1) & 3)) << 3);
      ah[i] = *(const bshort8*)&AsH[off];
      al[i] = *(const bshort8*)&AsL[off];
    }
    #pragma unroll
    for (int j = 0; j < 2; j++) {
      int R = nbase + j * 16 + r;
      int off = R * 32 + ((g ^ ((R >> 1) & 3)) << 3);
      bh[j] = *(const bshort8*)&WsH[off];
      bl[j] = *(const bshort8*)&WsL[off];
    }
    #pragma unroll
    for (int i = 0; i < 4; i++)
      #pragma unroll
      for (int j = 0; j < 2; j++) {
        acc[i][j] = __builtin_amdgcn_mfma_f32_16x16x32_bf16(ah[i], bh[j], acc[i][j], 0, 0, 0);
        acc[i][j] = __builtin_amdgcn_mfma_f32_16x16x32_bf16(ah[i], bl[j], acc[i][j], 0, 0, 0);
        acc[i][j] = __builtin_amdgcn_mfma_f32_16x16x32_bf16(al[i], bh[j], acc[i][j], 0, 0, 0);
      }
    __syncthreads();
  }
  // epilogue: C/D layout col=lane&15, row=(lane>>4)*4+reg (HW-verified)
  #pragma unroll
  for (int j = 0; j < 2; j++) {
    int gcol = n0 + nbase + j * 16 + r;
    float bv = bias[gcol];
    #pragma unroll
    for (int i = 0; i < 4; i++) {
      #pragma unroll
      for (int rg = 0; rg < 4; rg++) {
        int grow = m0 + mbase + i * 16 + g * 4 + rg;
        Cm[(size_t)grow * N + gcol] = acc[i][j][rg] + bv;
      }
    }
  }
}

// ---------------- LSTM scan ----------------
// R11 post-mortem: batched-MFMA collapsed parallelism (16 blocks, 1.5% occ,
// 303us) -> reverted to the proven 512-thread readlane structure (183us).
// R12 change: FAST activations (fsigm/ftanh, __expf-based). The activation
// phase runs on only 2 of 8 waves while 6 wait at the barrier -- library
// expf/tanhf (~25-40 instr each x5) put ~500-700 cyc/step on the critical
// path; fast versions (~4 ops) cut that to ~100. Numerically verified safe
// by R11's pass (same absmax with these activations).
__global__ __launch_bounds__(512, 1) void k_lstm(const float* __restrict__ xg,
    const float* __restrict__ whhF, const float* __restrict__ whhB,
    float* __restrict__ hs)
{
  int b = blockIdx.x, q = blockIdx.y, dir = q & 1;
  const float* whh = dir ? whhB : whhF;
  const float* xgq = xg + ((size_t)(q * B_ + b)) * (S_ * G4);
  float* out = hs + ((size_t)(q * B_ + b)) * SH;
  int j = threadIdx.x;
  int lane = j & 63;

  float w[128];
  #pragma unroll
  for (int k = 0; k < 128; k += 4) {
    float4 v = *(const float4*)(whh + (size_t)j * 128 + k);
    w[k] = v.x; w[k + 1] = v.y; w[k + 2] = v.z; w[k + 3] = v.w;
  }
  __shared__ float hsm[128];
  __shared__ float csm[128];
  __shared__ float gsm[512];
  if (j < 128) { hsm[j] = 0.f; csm[j] = 0.f; }
  __syncthreads();

  float h0 = 0.f, h1 = 0.f;
  float xnext = xgq[(size_t)(dir ? (S_ - 1) : 0) * G4 + j];

  for (int st = 0; st < S_; st++) {
    int tt = dir ? (S_ - 1 - st) : st;
    float xcur = xnext;
    {
      int stn = (st + 1 < S_) ? st + 1 : st;
      int ttn = dir ? (S_ - 1 - stn) : stn;
      xnext = xgq[(size_t)ttn * G4 + j];
    }
    float a0 = xcur, a1 = 0.f, a2 = 0.f, a3 = 0.f;
    #pragma unroll
    for (int k = 0; k < 64; k += 4) {
      a0 += w[k]     * blane(h0, k);
      a1 += w[k + 1] * blane(h0, k + 1);
      a2 += w[k + 2] * blane(h0, k + 2);
      a3 += w[k + 3] * blane(h0, k + 3);
    }
    #pragma unroll
    for (int k = 0; k < 64; k += 4) {
      a0 += w[64 + k]     * blane(h1, k);
      a1 += w[64 + k + 1] * blane(h1, k + 1);
      a2 += w[64 + k + 2] * blane(h1, k + 2);
      a3 += w[64 + k + 3] * blane(h1, k + 3);
    }
    gsm[j] = (a0 + a1) + (a2 + a3);
    __syncthreads();
    if (j < 128) {
      float ig = fsigm(gsm[j]);
      float fg = fsigm(gsm[128 + j]);
      float gg = ftanh(gsm[256 + j]);
      float og = fsigm(gsm[384 + j]);
      float c = fg * csm[j] + ig * gg;
      float hn = og * ftanh(c);
      csm[j] = c; hsm[j] = hn;
      out[(size_t)tt * H_ + j] = hn;
    }
    __syncthreads();
    h0 = hsm[lane];
    h1 = hsm[64 + lane];
  }
}

// ---------------- full matching ----------------
__global__ __launch_bounds__(256) void k_full(const float* __restrict__ C,
    const float* __restrict__ w1, const float* __restrict__ w2,
    float* __restrict__ ag1, float* __restrict__ ag2)
{
  int b = blockIdx.x, q = blockIdx.y, dir = q & 1;
  const float* p1  = C + (size_t)q * BSH + (size_t)b * SH;
  const float* p2l = C + (size_t)((q + 2) & 3) * BSH + (size_t)b * SH + (size_t)(S_ - 1) * H_;
  const float* w = dir ? w2 : w1;
  float* out = (q < 2 ? ag1 : ag2) + (size_t)b * S_ * 160;

  __shared__ float p1s[SH];
  __shared__ float ws2[H_][L_];
  __shared__ float p2s[H_];
  __shared__ float n2s[L_];
  int t = threadIdx.x;
  for (int i = t; i < SH; i += 256) p1s[i] = p1[i];
  for (int i = t; i < H_ * L_; i += 256) { float v = w[i]; ws2[i / L_][i % L_] = v * v; }
  if (t < H_) p2s[t] = p2l[t];
  __syncthreads();
  if (t < L_) {
    float s = 0.f;
    for (int hh = 0; hh < H_; hh++) { float v = p2s[hh]; s += v * v * ws2[hh][t]; }
    n2s[t] = sqrtf(s);
  }
  __syncthreads();
  for (int i = t; i < S_ * L_; i += 256) {
    int s = i / L_, l = i % L_;
    const float* pr = p1s + s * H_;
    float dot = 0.f, n1 = 0.f;
    for (int hh = 0; hh < H_; hh++) {
      float a = pr[hh], ww = ws2[hh][l];
      dot += a * p2s[hh] * ww;
      n1 += a * a * ww;
    }
    n1 = sqrtf(n1);
    out[(size_t)s * 160 + dir * L_ + l] = dot / (fmaxf(n1, EPSV) * fmaxf(n2s[l], EPSV));
  }
}

// ---------------- maxpool matching (bf16 MFMA) ----------------
__global__ __launch_bounds__(512, 1) void k_maxpool(const float* __restrict__ C,
    const float* __restrict__ w3, const float* __restrict__ w4,
    float* __restrict__ ag1, float* __restrict__ ag2)
{
  int b = blockIdx.x, dir = blockIdx.y, lh = blockIdx.z;
  const float* p1 = C + (size_t)(0 + dir) * BSH + (size_t)b * SH;
  const float* p2 = C + (size_t)(2 + dir) * BSH + (size_t)b * SH;
  const float* w = dir ? w4 : w3;

  __shared__ __align__(16) short P1b[128 * 128];
  __shared__ __align__(16) short P2b[128 * 128];
  __shared__ __align__(16) short Ab[128 * 128];
  __shared__ float w2s[128 * 10];
  __shared__ float n1s[128], n2s[128];
  __shared__ unsigned mx2u[128];

  int t = threadIdx.x;
  int wv = t >> 6, lane = t & 63;
  int g = lane >> 4, col = lane & 15;

  for (int i = t; i < 8192; i += 512) {
    int row = i >> 6, hp = i & 63;
    int phys = bswz(row, hp >> 2) + ((hp & 3) << 1);
    float2 v1 = *(const float2*)&p1[(row << 7) + (hp << 1)];
    float2 v2 = *(const float2*)&p2[(row << 7) + (hp << 1)];
    *(unsigned*)&P1b[phys] = (unsigned)f2bf(v1.x) | ((unsigned)f2bf(v1.y) << 16);
    *(unsigned*)&P2b[phys] = (unsigned)f2bf(v2.x) | ((unsigned)f2bf(v2.y) << 16);
  }
  for (int i = t; i < 128 * 10; i += 512) {
    int hh = i / 10, lq = i % 10;
    float wv_ = w[hh * L_ + lh * 10 + lq];
    w2s[i] = wv_ * wv_;
  }
  __syncthreads();

  #pragma unroll 1
  for (int lq = 0; lq < 10; lq++) {
    int lout = lh * 10 + lq;
    for (int i = t; i < 8192; i += 512) {
      int row = i >> 6, hp = i & 63;
      int phys = bswz(row, hp >> 2) + ((hp & 3) << 1);
      unsigned u = *(const unsigned*)&P1b[phys];
      float lo = bf2f((unsigned short)(u & 0xffffu)) * w2s[(hp << 1) * 10 + lq];
      float hi = bf2f((unsigned short)(u >> 16))     * w2s[((hp << 1) + 1) * 10 + lq];
      *(unsigned*)&Ab[phys] = (unsigned)f2bf(lo) | ((unsigned)f2bf(hi) << 16);
    }
    {
      int s = t >> 2, part = t & 3;
      float s1 = 0.f, s2 = 0.f;
      #pragma unroll 1
      for (int hp = part * 16; hp < part * 16 + 16; hp++) {
        int phys = bswz(s, hp >> 2) + ((hp & 3) << 1);
        unsigned u1 = *(const unsigned*)&P1b[phys];
        unsigned u2 = *(const unsigned*)&P2b[phys];
        float wlo = w2s[(hp << 1) * 10 + lq];
        float whi = w2s[((hp << 1) + 1) * 10 + lq];
        float a = bf2f((unsigned short)(u1 & 0xffffu)), bb = bf2f((unsigned short)(u1 >> 16));
        float c2 = bf2f((unsigned short)(u2 & 0xffffu)), d2 = bf2f((unsigned short)(u2 >> 16));
        s1 += a * a * wlo + bb * bb * whi;
        s2 += c2 * c2 * wlo + d2 * d2 * whi;
      }
      s1 += __shfl_xor(s1, 1, 64); s1 += __shfl_xor(s1, 2, 64);
      s2 += __shfl_xor(s2, 1, 64); s2 += __shfl_xor(s2, 2, 64);
      if (part == 0) { n1s[s] = sqrtf(s1); n2s[s] = sqrtf(s2); }
    }
    if (t < 128) mx2u[t] = fmap(-3.4e38f);
    __syncthreads();

    {
      int mrow = (wv << 4) + col;
      f32x4 acc0 = {0,0,0,0}, acc1 = {0,0,0,0}, acc2 = {0,0,0,0}, acc3 = {0,0,0,0};
      f32x4 acc4 = {0,0,0,0}, acc5 = {0,0,0,0}, acc6 = {0,0,0,0}, acc7 = {0,0,0,0};
      #pragma unroll 1
      for (int k0 = 0; k0 < 128; k0 += 32) {
        int slot = ((k0 >> 3) + g) ^ col;
        bshort8 av = *(const bshort8*)&Ab[(mrow << 7) + (slot << 3)];
        bshort8 bv0 = *(const bshort8*)&P2b[((0 << 4) + col << 7) + (slot << 3)];
        bshort8 bv1 = *(const bshort8*)&P2b[(((1 << 4) + col) << 7) + (slot << 3)];
        bshort8 bv2 = *(const bshort8*)&P2b[(((2 << 4) + col) << 7) + (slot << 3)];
        bshort8 bv3 = *(const bshort8*)&P2b[(((3 << 4) + col) << 7) + (slot << 3)];
        bshort8 bv4 = *(const bshort8*)&P2b[(((4 << 4) + col) << 7) + (slot << 3)];
        bshort8 bv5 = *(const bshort8*)&P2b[(((5 << 4) + col) << 7) + (slot << 3)];
        bshort8 bv6 = *(const bshort8*)&P2b[(((6 << 4) + col) << 7) + (slot << 3)];
        bshort8 bv7 = *(const bshort8*)&P2b[(((7 << 4) + col) << 7) + (slot << 3)];
        acc0 = __builtin_amdgcn_mfma_f32_16x16x32_bf16(av, bv0, acc0, 0, 0, 0);
        acc1 = __builtin_amdgcn_mfma_f32_16x16x32_bf16(av, bv1, acc1, 0, 0, 0);
        acc2 = __builtin_amdgcn_mfma_f32_16x16x32_bf16(av, bv2, acc2, 0, 0, 0);
        acc3 = __builtin_amdgcn_mfma_f32_16x16x32_bf16(av, bv3, acc3, 0, 0, 0);
        acc4 = __builtin_amdgcn_mfma_f32_16x16x32_bf16(av, bv4, acc4, 0, 0, 0);
        acc5 = __builtin_amdgcn_mfma_f32_16x16x32_bf16(av, bv5, acc5, 0, 0, 0);
        acc6 = __builtin_amdgcn_mfma_f32_16x16x32_bf16(av, bv6, acc6, 0, 0, 0);
        acc7 = __builtin_amdgcn_mfma_f32_16x16x32_bf16(av, bv7, acc7, 0, 0, 0);
      }
      float n1v[4];
      #pragma unroll
      for (int r = 0; r < 4; r++) n1v[r] = n1s[(wv << 4) + (g << 2) + r];
      float rm[4] = {-3.4e38f, -3.4e38f, -3.4e38f, -3.4e38f};
      float cm[8];
      f32x4 accs[8] = {acc0, acc1, acc2, acc3, acc4, acc5, acc6, acc7};
      #pragma unroll
      for (int c = 0; c < 8; c++) {
        float n2v = n2s[(c << 4) + col];
        float cmx = -3.4e38f;
        #pragma unroll
        for (int r = 0; r < 4; r++) {
          float deno = n1v[r] * n2v;
          float cs = accs[c][r] / (deno > EPSV ? deno : EPSV);
          rm[r] = fmaxf(rm[r], cs);
          cmx = fmaxf(cmx, cs);
        }
        cm[c] = cmx;
      }
      #pragma unroll
      for (int m = 1; m < 16; m <<= 1)
        #pragma unroll
        for (int r = 0; r < 4; r++) rm[r] = fmaxf(rm[r], __shfl_xor(rm[r], m, 64));
      if (col == 0) {
        #pragma unroll
        for (int r = 0; r < 4; r++) {
          int srow = (wv << 4) + (g << 2) + r;
          ag1[(size_t)b * S_ * 160 + (size_t)srow * 160 + 40 + dir * L_ + lout] = rm[r];
        }
      }
      #pragma unroll
      for (int c = 0; c < 8; c++) {
        cm[c] = fmaxf(cm[c], __shfl_xor(cm[c], 16, 64));
        cm[c] = fmaxf(cm[c], __shfl_xor(cm[c], 32, 64));
      }
      if (lane < 16) {
        #pragma unroll
        for (int c = 0; c < 8; c++) atomicMax(&mx2u[(c << 4) + lane], fmap(cm[c]));
      }
    }
    __syncthreads();
    if (t < 128)
      ag2[(size_t)b * S_ * 160 + (size_t)t * 160 + 40 + dir * L_ + lout] = funmap(mx2u[t]);
    __syncthreads();
  }
}

// ---------------- alpha (plain cosine matrix) ----------------
__global__ __launch_bounds__(256, 1) void k_alpha(const float* __restrict__ C,
                                                  float* __restrict__ alpha)
{
  int b = blockIdx.x, dir = blockIdx.y;
  const float* p1 = C + (size_t)(0 + dir) * BSH + (size_t)b * SH;
  const float* p2 = C + (size_t)(2 + dir) * BSH + (size_t)b * SH;
  __shared__ __align__(16) float a1[128 * 64];
  __shared__ __align__(16) float a2[128 * 64];
  __shared__ float n1p[128], n2p[128];
  int t = threadIdx.x, tx = t & 15, ty = t >> 4;
  float acc[8][8] = {};

  for (int pass = 0; pass < 2; pass++) {
    int h0 = pass << 6;
    for (int i = t; i < 128 * 64; i += 256) {
      int row = i >> 6, hh = i & 63;
      int off = swz64(row, hh);
      a1[off] = p1[(size_t)row * H_ + h0 + hh];
      a2[off] = p2[(size_t)row * H_ + h0 + hh];
    }
    __syncthreads();
    {
      int r = t & 127;
      const float* a = (t < 128) ? a1 : a2;
      float s = 0.f;
      #pragma unroll 1
      for (int f = 0; f < 16; f++) {
        float4 v = *(const float4*)&a[(r << 6) + ((f ^ ((r >> 3) & 15)) << 2)];
        s += dot4(v, v);
      }
      float* np = (t < 128) ? n1p : n2p;
      if (pass == 0) np[r] = s; else np[r] += s;
    }
    #pragma unroll 1
    for (int f = 0; f < 16; f++) {
      int cx = ((f ^ ty) << 2);
      int cy = ((f ^ tx) << 2);
      float4 x[8], y[8];
      #pragma unroll
      for (int i = 0; i < 8; i++) x[i] = *(const float4*)&a1[((8 * ty + i) << 6) + cx];
      #pragma unroll
      for (int j = 0; j < 8; j++) y[j] = *(const float4*)&a2[((8 * tx + j) << 6) + cy];
      #pragma unroll
      for (int i = 0; i < 8; i++)
        #pragma unroll
        for (int j = 0; j < 8; j++) acc[i][j] += dot4(x[i], y[j]);
    }
    __syncthreads();
  }
  float inv1[8], inv2[8];
  #pragma unroll
  for (int i = 0; i < 8; i++) inv1[i] = 1.f / fmaxf(sqrtf(n1p[8 * ty + i]), EPSV);
  #pragma unroll
  for (int j = 0; j < 8; j++) inv2[j] = 1.f / fmaxf(sqrtf(n2p[8 * tx + j]), EPSV);
  float* outp = alpha + ((size_t)dir * B_ + b) * SH;
  #pragma unroll
  for (int i = 0; i < 8; i++) {
    int ss = 8 * ty + i;
    float s1 = inv1[i];
    float4 o0 = make_float4(acc[i][0] * s1 * inv2[0], acc[i][1] * s1 * inv2[1],
                            acc[i][2] * s1 * inv2[2], acc[i][3] * s1 * inv2[3]);
    float4 o1 = make_float4(acc[i][4] * s1 * inv2[4], acc[i][5] * s1 * inv2[5],
                            acc[i][6] * s1 * inv2[6], acc[i][7] * s1 * inv2[7]);
    *(float4*)&outp[(size_t)ss * S_ + 8 * tx] = o0;
    *(float4*)&outp[(size_t)ss * S_ + 8 * tx + 4] = o1;
  }
}

// ---------------- attentive matching ----------------
__global__ __launch_bounds__(256, 1) void k_att(const float* __restrict__ C,
    const float* __restrict__ alpha,
    const float* __restrict__ w5, const float* __restrict__ w6,
    const float* __restrict__ w7, const float* __restrict__ w8,
    float* __restrict__ ag1, float* __restrict__ ag2)
{
  int b = blockIdx.x, q = blockIdx.y, dir = q & 1;
  const float* p1  = C + (size_t)q * BSH + (size_t)b * SH;
  const float* m2g = C + (size_t)((q + 2) & 3) * BSH + (size_t)b * SH;
  const float* wa = dir ? w6 : w5;
  const float* wm = dir ? w8 : w7;
  const float* ain = alpha + ((size_t)dir * B_ + b) * SH;
  float* out = (q < 2 ? ag1 : ag2) + (size_t)b * S_ * 160;
  bool tr = (q >= 2);

  __shared__ __align__(16) float A[128 * 128];
  __shared__ __align__(16) float M2T[128 * 128];
  __shared__ __align__(16) float waT[20 * 128];
  __shared__ __align__(16) float wmT[20 * 128];
  __shared__ float rowsum[128];
  __shared__ int   midx[128];
  int t = threadIdx.x, tx = t & 15, ty = t >> 4;

  for (int i = t; i < SH; i += 256) {
    int r = i >> 7, c = i & 127;
    float av = ain[i];
    if (tr) A[swz128(c, r)] = av; else A[swz128(r, c)] = av;
    M2T[swz128(c, r)] = m2g[i];
  }
  for (int i = t; i < H_ * L_; i += 256) {
    int hh = i / L_, l = i % L_;
    float v = wa[i]; waT[l * 128 + hh] = v * v;
    float u = wm[i]; wmT[l * 128 + hh] = u * u;
  }
  __syncthreads();

  if (t < 128) {
    float sum = 0.f, best = -3.4e38f; int bi = 0;
    #pragma unroll 1
    for (int f = 0; f < 32; f++) {
      float4 v = *(const float4*)&A[(t << 7) + (((f ^ ((t >> 3) & 15)) & 31) << 2)];
      sum += v.x + v.y + v.z + v.w;
      int k = f << 2;
      if (v.x > best) { best = v.x; bi = k; }
      if (v.y > best) { best = v.y; bi = k + 1; }
      if (v.z > best) { best = v.z; bi = k + 2; }
      if (v.w > best) { best = v.w; bi = k + 3; }
    }
    rowsum[t] = sum; midx[t] = bi;
  }
  __syncthreads();

  float acc[8][8] = {};
  #pragma unroll 1
  for (int f = 0; f < 32; f++) {
    int cx = (((f ^ ty) & 31) << 2);
    int cy = (((f ^ tx) & 31) << 2);
    float4 x[8], y[8];
    #pragma unroll
    for (int i = 0; i < 8; i++) x[i] = *(const float4*)&A[((8 * ty + i) << 7) + cx];
    #pragma unroll
    for (int j = 0; j < 8; j++) y[j] = *(const float4*)&M2T[((8 * tx + j) << 7) + cy];
    #pragma unroll
    for (int i = 0; i < 8; i++)
      #pragma unroll
      for (int j = 0; j < 8; j++) acc[i][j] += dot4(x[i], y[j]);
  }
  __syncthreads();
  {
    float rinv[8];
    #pragma unroll
    for (int i = 0; i < 8; i++) rinv[i] = 1.f / rowsum[8 * ty + i];
    #pragma unroll
    for (int i = 0; i < 8; i++) {
      int row = 8 * ty + i;
      int f0 = (2 * tx) ^ ((row >> 3) & 15);
      int f1 = (2 * tx + 1) ^ ((row >> 3) & 15);
      float4 o0 = make_float4(acc[i][0] * rinv[i], acc[i][1] * rinv[i],
                              acc[i][2] * rinv[i], acc[i][3] * rinv[i]);
      float4 o1 = make_float4(acc[i][4] * rinv[i], acc[i][5] * rinv[i],
                              acc[i][6] * rinv[i], acc[i][7] * rinv[i]);
      *(float4*)&A[(row << 7) + (f0 << 2)] = o0;
      *(float4*)&A[(row << 7) + (f1 << 2)] = o1;
    }
  }
  __syncthreads();

  {
    int s = t >> 1, l0 = (t & 1) * 10;
    int mi = midx[s];
    const float* m2r = m2g + (size_t)mi * H_;
    const float* p1r = p1 + (size_t)s * H_;
    float dA[10] = {}, nA[10] = {}, bA[10] = {};
    float dM[10] = {}, nM[10] = {}, bM[10] = {};
    #pragma unroll 1
    for (int f = 0; f < 32; f++) {
      float4 pv = *(const float4*)&p1r[f << 2];
      float4 mv = *(const float4*)&m2r[f << 2];
      float4 av = *(const float4*)&A[(s << 7) + (((f ^ ((s >> 3) & 15)) & 31) << 2)];
      float4 ap = make_float4(av.x*pv.x, av.y*pv.y, av.z*pv.z, av.w*pv.w);
      float4 a2 = make_float4(av.x*av.x, av.y*av.y, av.z*av.z, av.w*av.w);
      float4 p2 = make_float4(pv.x*pv.x, pv.y*pv.y, pv.z*pv.z, pv.w*pv.w);
      float4 mp = make_float4(mv.x*pv.x, mv.y*pv.y, mv.z*pv.z, mv.w*pv.w);
      float4 m2 = make_float4(mv.x*mv.x, mv.y*mv.y, mv.z*mv.z, mv.w*mv.w);
      #pragma unroll
      for (int l = 0; l < 10; l++) {
        float4 wv = *(const float4*)&waT[(l0 + l) * 128 + (f << 2)];
        dA[l] += dot4(ap, wv); nA[l] += dot4(a2, wv); bA[l] += dot4(p2, wv);
        float4 uv = *(const float4*)&wmT[(l0 + l) * 128 + (f << 2)];
        dM[l] += dot4(mp, uv); nM[l] += dot4(m2, uv); bM[l] += dot4(p2, uv);
      }
    }
    #pragma unroll
    for (int l = 0; l < 10; l++) {
      int ll = l0 + l;
      out[(size_t)s * 160 + 80  + dir * L_ + ll] =
          dA[l] / (fmaxf(sqrtf(nA[l]), EPSV) * fmaxf(sqrtf(bA[l]), EPSV));
      out[(size_t)s * 160 + 120 + dir * L_ + ll] =
          dM[l] / (fmaxf(sqrtf(nM[l]), EPSV) * fmaxf(sqrtf(bM[l]), EPSV));
    }
  }
}

// ---------------- final MLP ----------------
__global__ __launch_bounds__(256) void k_final(const float* __restrict__ Cc,
    const float* __restrict__ pW1, const float* __restrict__ pb1,
    const float* __restrict__ pW2, const float* __restrict__ pb2,
    float* __restrict__ out)
{
  int b = blockIdx.x, t = threadIdx.x;
  __shared__ float cat[512];
  __shared__ float hid[256];
  if (t < 128) {
    cat[t]       = Cc[(size_t)(0 * B_ + b) * SH + (size_t)(S_ - 1) * H_ + t];
    cat[128 + t] = Cc[(size_t)(1 * B_ + b) * SH + (size_t)(S_ - 1) * H_ + t];
    cat[256 + t] = Cc[(size_t)(2 * B_ + b) * SH + (size_t)(S_ - 1) * H_ + t];
    cat[384 + t] = Cc[(size_t)(3 * B_ + b) * SH + (size_t)(S_ - 1) * H_ + t];
  }
  __syncthreads();
  float a = pb1[t];
  for (int k = 0; k < 512; k++) a += cat[k] * pW1[(size_t)t * 512 + k];
  hid[t] = fmaxf(a, 0.f);
  __syncthreads();
  if (t < 3) {
    float o = pb2[t];
    for (int k = 0; k < 256; k++) o += hid[k] * pW2[(size_t)t * 256 + k];
    out[(size_t)b * 3 + t] = o;
  }
}

// ---------------- launch ----------------
extern "C" void kernel_launch(void* const* d_in, const int* in_sizes, int n_in,
                              void* d_out, int out_size, void* d_ws, size_t ws_size,
                              hipStream_t stream)
{
  const float* emb    = (const float*)d_in[0];
  const float* cwih_f = (const float*)d_in[1];
  const float* cwhh_f = (const float*)d_in[2];
  const float* cb_f   = (const float*)d_in[3];
  const float* cwih_b = (const float*)d_in[4];
  const float* cwhh_b = (const float*)d_in[5];
  const float* cb_b   = (const float*)d_in[6];
  const float* awih_f = (const float*)d_in[7];
  const float* awhh_f = (const float*)d_in[8];
  const float* ab_f   = (const float*)d_in[9];
  const float* awih_b = (const float*)d_in[10];
  const float* awhh_b = (const float*)d_in[11];
  const float* ab_b   = (const float*)d_in[12];
  const float* pW1    = (const float*)d_in[13];
  const float* pb1    = (const float*)d_in[14];
  const float* pW2    = (const float*)d_in[15];
  const float* pb2    = (const float*)d_in[16];
  const int*   pidx   = (const int*)d_in[17];
  const int*   hidx   = (const int*)d_in[18];
  const float* w1 = (const float*)d_in[19];
  const float* w2 = (const float*)d_in[20];
  const float* w3 = (const float*)d_in[21];
  const float* w4 = (const float*)d_in[22];
  const float* w5 = (const float*)d_in[23];
  const float* w6 = (const float*)d_in[24];
  const float* w7 = (const float*)d_in[25];
  const float* w8 = (const float*)d_in[26];

  float* ws = (float*)d_ws;
  float* XG   = ws;
  float* X1   = ws + 16777216;
  float* X2   = X1 + 2457600;
  float* ALPH = X1;
  float* AG1  = ws + 16777216 + 2097152;
  float* AG2  = AG1 + (size_t)B_ * S_ * 160;
  float* CC   = ws + 21692416;

  k_embed<<<dim3(B_ * S_, 2), 256, 0, stream>>>(emb, pidx, hidx, X1, X2);
  gemm_abt<D_><<<dim3(64, 4, 4), 512, 0, stream>>>(X1, X2, cwih_f, cwih_b, cb_f, cb_b,
                                                   XG, B_ * S_, G4);
  k_lstm<<<dim3(B_, 4), 512, 0, stream>>>(XG, cwhh_f, cwhh_b, CC);
  k_full<<<dim3(B_, 4), 256, 0, stream>>>(CC, w1, w2, AG1, AG2);
  k_maxpool<<<dim3(B_, 2, 2), 512, 0, stream>>>(CC, w3, w4, AG1, AG2);
  k_alpha<<<dim3(B_, 2), 256, 0, stream>>>(CC, ALPH);
  k_att<<<dim3(B_, 4), 256, 0, stream>>>(CC, ALPH, w5, w6, w7, w8, AG1, AG2);
  gemm_abt<8 * L_><<<dim3(64, 4, 4), 512, 0, stream>>>(AG1, AG2, awih_f, awih_b, ab_f, ab_b,
                                                       XG, B_ * S_, G4);
  k_lstm<<<dim3(B_, 4), 512, 0, stream>>>(XG, awhh_f, awhh_b, CC);
  k_final<<<dim3(B_), 256, 0, stream>>>(CC, pW1, pb1, pW2, pb2, (float*)d_out);
}